// Round 14
// baseline (83.314 us; speedup 1.0000x reference)
//
#include <hip/hip_runtime.h>
#include <math.h>

// Problem constants
#define NBATCH 4
#define NCLS   19
#define HWDIM  512
#define HW     (512 * 512)      // 262144
#define PH     171              // pooled H=W
#define PHP    176              // padded row stride (16B-aligned rows)
#define PP2A   (171 * 176)      // 30096 floats per (n,c) plane
#define NHW    169              // PH - radius + 1
#define MM     (169 * 169)      // 28561
#define NNC    (NBATCH * NCLS)  // 76

typedef float f4  __attribute__((ext_vector_type(4)));
typedef float f2v __attribute__((ext_vector_type(2)));

// ---------------------------------------------------------------------------
// Stage 1 (round-6/9 measured-best, + 16-float guard zeroing before P):
// fused softmax + one-hot + 3x3/stride-3 avg-pool (pad=1, /9).
// ---------------------------------------------------------------------------
__global__ __launch_bounds__(512) void stage1_pool(
    const float* __restrict__ cls, const int* __restrict__ label,
    float* __restrict__ guard, float* __restrict__ P, float* __restrict__ L) {
  if (blockIdx.x == 0 && threadIdx.x < 16) guard[threadIdx.x] = 0.f;

  int n  = blockIdx.x / PH;
  int ph = blockIdx.x - n * PH;
  int col = threadIdx.x;  // input column 0..511

  float vv[3][NCLS];
  int lbs[3];
#pragma unroll
  for (int i = 0; i < 3; ++i) {
    int r = 3 * ph - 1 + i;
    bool ok = (r >= 0) && (r < HWDIM);
    if (ok) {
      lbs[i] = label[((size_t)n * HWDIM + r) * HWDIM + col];
      const float* base = cls + (size_t)n * NCLS * HW + (size_t)r * HWDIM + col;
#pragma unroll
      for (int c = 0; c < NCLS; ++c) vv[i][c] = base[(size_t)c * HW];
    } else {
      lbs[i] = -1;
#pragma unroll
      for (int c = 0; c < NCLS; ++c) vv[i][c] = 0.f;
    }
  }

  float accP[NCLS], accL[NCLS];
#pragma unroll
  for (int c = 0; c < NCLS; ++c) { accP[c] = 0.f; accL[c] = 0.f; }
#pragma unroll
  for (int i = 0; i < 3; ++i) {
    int lb = lbs[i];
    float mx = vv[i][0];
#pragma unroll
    for (int c = 1; c < NCLS; ++c) mx = fmaxf(mx, vv[i][c]);
    float se = 0.f;
    float ex[NCLS];
#pragma unroll
    for (int c = 0; c < NCLS; ++c) {
      ex[c] = __expf(vv[i][c] - mx);
      se += ex[c];
    }
    float m = (lb >= 0 && lb < NCLS) ? 1.f : 0.f;
    float inv = m / se;
#pragma unroll
    for (int c = 0; c < NCLS; ++c) {
      accP[c] += ex[c] * inv;
      accL[c] += (lb == c) ? 1.f : 0.f;
    }
  }

  __shared__ float xbP[10][516];
  __shared__ float xbL[10][516];
  const float inv9 = 1.f / 9.f;
#pragma unroll
  for (int c0 = 0; c0 < NCLS; c0 += 10) {
#pragma unroll
    for (int cc = 0; cc < 10; ++cc) {
      if (c0 + cc < NCLS) {
        xbP[cc][1 + col] = accP[(c0 + cc) < NCLS ? (c0 + cc) : 0];
        xbL[cc][1 + col] = accL[(c0 + cc) < NCLS ? (c0 + cc) : 0];
        if (col == 0) { xbP[cc][0] = 0.f; xbL[cc][0] = 0.f; }
      }
    }
    __syncthreads();
    if (col < PH) {
      int pw = col;
#pragma unroll
      for (int cc = 0; cc < 10; ++cc) {
        if (c0 + cc < NCLS) {
          int c = c0 + cc;
          float sP = xbP[cc][3 * pw] + xbP[cc][3 * pw + 1] + xbP[cc][3 * pw + 2];
          float sL = xbL[cc][3 * pw] + xbL[cc][3 * pw + 1] + xbL[cc][3 * pw + 2];
          size_t o = ((size_t)(n * NCLS + c)) * PP2A + (size_t)ph * PHP + pw;
          P[o] = sP * inv9;
          L[o] = sL * inv9;
        }
      }
    } else if (col < PHP) {
#pragma unroll
      for (int cc = 0; cc < 10; ++cc) {
        if (c0 + cc < NCLS) {
          int c = c0 + cc;
          size_t o = ((size_t)(n * NCLS + c)) * PP2A + (size_t)ph * PHP + col;
          P[o] = 0.f;
          L[o] = 0.f;
        }
      }
    }
    __syncthreads();
  }
}

// ---------------------------------------------------------------------------
// Stage 2: OFFSET-CORRELATION TOTALS over the full zero-extended 171x171
// domain. For shifted-window moments, Sum_m F[m+d]*G[m+e] depends only on
// a = e-d up to boundary strips -> 25 cross offsets, 13 self (not 81/45).
// Parts (grid y): 0 selfX(la)+TX | 1 selfY(pr)+TY | 2 cross pr*la (25).
// Totals record per nc (64 f32): [0] TX | [1] TY | [2..14] TXX(D13) |
// [15..27] TYY | [28..52] TYX (j=(ay+2)*5+ax+2).
// D13 enumeration: idx = ax (ay=0, ax 0..2), 5+ax (ay=1), 10+ax (ay=2).
// ---------------------------------------------------------------------------
__device__ __forceinline__ void ldrow7(f2v (&W)[7], const float* X, int row,
                                       int x0) {
  if (row >= 0 && row <= 170) {
    const float* p = X + (ptrdiff_t)row * PHP + x0;
    f2v a = *(const f2v*)(p - 2);
    f2v b = *(const f2v*)(p);
    f2v c = *(const f2v*)(p + 2);
    f2v d = *(const f2v*)(p + 4);
    W[0] = a; W[2] = b; W[4] = c; W[6] = d;
    W[1] = (f2v){a.y, b.x}; W[3] = (f2v){b.y, c.x}; W[5] = (f2v){c.y, d.x};
  } else {
#pragma unroll
    for (int j = 0; j < 7; ++j) W[j] = (f2v){0.f, 0.f};
  }
}

__device__ __forceinline__ void ldy2(f2v& a, f2v& b, const float* Y, int row,
                                     int x0) {
  const float* p = Y + (size_t)row * PHP + x0;
  a = *(const f2v*)p;
  b = *(const f2v*)(p + 2);
}

__device__ __forceinline__ void fma_self13(f2v (&acc)[14],
    const f2v (&c0)[7], const f2v (&c1)[7], const f2v (&c2)[7]) {
  acc[13] += c0[2]; acc[13] += c0[4];
#pragma unroll
  for (int i = 0; i < 3; ++i) {
    acc[i] += c0[2] * c0[2 + i];
    acc[i] += c0[4] * c0[4 + i];
  }
#pragma unroll
  for (int k = 0; k < 5; ++k) {
    acc[3 + k] += c0[2] * c1[k];
    acc[3 + k] += c0[4] * c1[k + 2];
  }
#pragma unroll
  for (int k = 0; k < 5; ++k) {
    acc[8 + k] += c0[2] * c2[k];
    acc[8 + k] += c0[4] * c2[k + 2];
  }
}

__device__ __forceinline__ void fma_cross25(f2v (&acc)[25],
    const f2v& ya, const f2v& yb,
    const f2v (&m2)[7], const f2v (&m1)[7], const f2v (&z0)[7],
    const f2v (&p1)[7], const f2v (&p2)[7]) {
#pragma unroll
  for (int k = 0; k < 5; ++k) {
    acc[k]      += ya * m2[k]; acc[k]      += yb * m2[k + 2];
    acc[5 + k]  += ya * m1[k]; acc[5 + k]  += yb * m1[k + 2];
    acc[10 + k] += ya * z0[k]; acc[10 + k] += yb * z0[k + 2];
    acc[15 + k] += ya * p1[k]; acc[15 + k] += yb * p1[k + 2];
    acc[20 + k] += ya * p2[k]; acc[20 + k] += yb * p2[k + 2];
  }
}

template <int NA>
__device__ __forceinline__ void epi_tot(f2v (&acc)[NA], float* red,
                                        float* __restrict__ tot, int nc,
                                        int mode /*0,1 self; 2 cross*/) {
  int tid  = threadIdx.x;
  int lane = tid & 63;
  int wid  = tid >> 6;  // 8 waves
#pragma unroll
  for (int k = 0; k < NA; ++k) {
    float v = acc[k].x + acc[k].y;
    v += __shfl_down(v, 32, 64);
    v += __shfl_down(v, 16, 64);
    v += __shfl_down(v, 8, 64);
    if (lane < 8) red[(wid * 8 + lane) * 28 + k] = v;
  }
  __syncthreads();
  if (tid < NA) {
    float sm = 0.f;
#pragma unroll
    for (int w = 0; w < 64; ++w) sm += red[w * 28 + tid];
    int off;
    if (mode == 2)      off = 28 + tid;
    else if (tid < 13)  off = (mode ? 15 : 2) + tid;
    else                off = mode ? 1 : 0;
    tot[(size_t)nc * 64 + off] = sm;
  }
}

__device__ void self_tot(const float* __restrict__ X, float* __restrict__ tot,
                         int nc, float* red, int mode) {
  f2v acc[14];
#pragma unroll
  for (int k = 0; k < 14; ++k) acc[k] = (f2v){0.f, 0.f};
  int tid = threadIdx.x;
  if (tid < 473) {
    int b = tid / 43, s = tid - b * 43;
    int x0 = 4 * s;                       // 0..168 (strip 42 hits zero pads)
    int u0 = (171 * b) / 11, u1 = (171 * (b + 1)) / 11;
    f2v A[7], B[7], C[7], D[7];
    ldrow7(A, X, u0, x0); ldrow7(B, X, u0 + 1, x0); ldrow7(C, X, u0 + 2, x0);
    int span = u1 - u0, nf = span & ~3, u = u0;
    for (int i = 0; i < nf; i += 4, u += 4) {
      ldrow7(D, X, u + 3, x0); fma_self13(acc, A, B, C);
      ldrow7(A, X, u + 4, x0); fma_self13(acc, B, C, D);
      ldrow7(B, X, u + 5, x0); fma_self13(acc, C, D, A);
      ldrow7(C, X, u + 6, x0); fma_self13(acc, D, A, B);
    }
    int r = span - nf;
    if (r > 0) { ldrow7(D, X, u + 3, x0); fma_self13(acc, A, B, C); }
    if (r > 1) { ldrow7(A, X, u + 4, x0); fma_self13(acc, B, C, D); }
    if (r > 2) { fma_self13(acc, C, D, A); }
  }
  epi_tot<14>(acc, red, tot, nc, mode);
}

__device__ void cross_tot(const float* __restrict__ Y,
                          const float* __restrict__ X,
                          float* __restrict__ tot, int nc, float* red) {
  f2v acc[25];
#pragma unroll
  for (int k = 0; k < 25; ++k) acc[k] = (f2v){0.f, 0.f};
  int tid = threadIdx.x;
  if (tid < 473) {
    int b = tid / 43, s = tid - b * 43;
    int x0 = 4 * s;
    int u0 = (171 * b) / 11, u1 = (171 * (b + 1)) / 11;
    f2v S0[7], S1[7], S2[7], S3[7], S4[7], S5[7];
    f2v y0a, y0b, y1a, y1b;
    ldrow7(S0, X, u0 - 2, x0); ldrow7(S1, X, u0 - 1, x0);
    ldrow7(S2, X, u0, x0);     ldrow7(S3, X, u0 + 1, x0);
    ldrow7(S4, X, u0 + 2, x0);
    ldy2(y0a, y0b, Y, u0, x0);
    int span = u1 - u0, nf = (span / 6) * 6, u = u0;
    for (int i = 0; i < nf; i += 6, u += 6) {
      ldrow7(S5, X, u + 3, x0); ldy2(y1a, y1b, Y, u + 1, x0);
      fma_cross25(acc, y0a, y0b, S0, S1, S2, S3, S4);
      ldrow7(S0, X, u + 4, x0); ldy2(y0a, y0b, Y, u + 2, x0);
      fma_cross25(acc, y1a, y1b, S1, S2, S3, S4, S5);
      ldrow7(S1, X, u + 5, x0); ldy2(y1a, y1b, Y, u + 3, x0);
      fma_cross25(acc, y0a, y0b, S2, S3, S4, S5, S0);
      ldrow7(S2, X, u + 6, x0); ldy2(y0a, y0b, Y, u + 4, x0);
      fma_cross25(acc, y1a, y1b, S3, S4, S5, S0, S1);
      ldrow7(S3, X, u + 7, x0); ldy2(y1a, y1b, Y, u + 5, x0);
      fma_cross25(acc, y0a, y0b, S4, S5, S0, S1, S2);
      ldrow7(S4, X, u + 8, x0); ldy2(y0a, y0b, Y, u + 6, x0);
      fma_cross25(acc, y1a, y1b, S5, S0, S1, S2, S3);
    }
    int r = span - nf;  // 0..5
    if (r > 0) { ldrow7(S5, X, u + 3, x0); ldy2(y1a, y1b, Y, u + 1, x0);
                 fma_cross25(acc, y0a, y0b, S0, S1, S2, S3, S4); }
    if (r > 1) { ldrow7(S0, X, u + 4, x0); ldy2(y0a, y0b, Y, u + 2, x0);
                 fma_cross25(acc, y1a, y1b, S1, S2, S3, S4, S5); }
    if (r > 2) { ldrow7(S1, X, u + 5, x0); ldy2(y1a, y1b, Y, u + 3, x0);
                 fma_cross25(acc, y0a, y0b, S2, S3, S4, S5, S0); }
    if (r > 3) { ldrow7(S2, X, u + 6, x0); ldy2(y0a, y0b, Y, u + 4, x0);
                 fma_cross25(acc, y1a, y1b, S3, S4, S5, S0, S1); }
    if (r > 4) { fma_cross25(acc, y0a, y0b, S4, S5, S0, S1, S2); }
  }
  epi_tot<25>(acc, red, tot, nc, 2);
}

__global__ __launch_bounds__(512) void stage2_tot(
    const float* __restrict__ P, const float* __restrict__ L,
    float* __restrict__ tot) {
  __shared__ float red[64 * 28];
  int nc = blockIdx.x;
  const float* Xla = L + (size_t)nc * PP2A;
  const float* Ypr = P + (size_t)nc * PP2A;
  if (blockIdx.y == 0)      self_tot(Xla, tot, nc, red, 0);
  else if (blockIdx.y == 1) self_tot(Ypr, tot, nc, red, 1);
  else                      cross_tot(Ypr, Xla, tot, nc, red);
}

// ---------------------------------------------------------------------------
// Stage 2b: boundary strips + inclusion-exclusion assembly -> CLASSIC record
// (s[0..8] sum la | [9..17] sum pr | [18..62] la*la UT45 | [63..107] pr*pr |
//  [108..188] pr[d]*la[e]) so stage3 stays byte-identical.
// S_rect(origin o) = Total - excluded-row strips - excluded-col strips
//                    + corner terms.  Excluded rows(oy): {169,170}/{0,170}/{0,1}.
// ---------------------------------------------------------------------------
__global__ __launch_bounds__(512) void stage2b_asm(
    const float* __restrict__ P, const float* __restrict__ L,
    const float* __restrict__ tot, float* __restrict__ cov) {
  __shared__ float rX[8 * 176], rY[8 * 176];
  __shared__ float cX[12 * 171], cY[12 * 171];
  __shared__ float sres[424];
  int nc = blockIdx.x, tid = threadIdx.x;
  const float* Xp = L + (size_t)nc * PP2A;  // la
  const float* Yp = P + (size_t)nc * PP2A;  // pr

  // rows {0,1,2,3,167,168,169,170} x 176
  for (int i = tid; i < 8 * 176; i += 512) {
    int rr = i / 176, c = i - rr * 176;
    int row = (rr < 4) ? rr : rr + 163;
    rX[i] = Xp[(size_t)row * PHP + c];
    rY[i] = Yp[(size_t)row * PHP + c];
  }
  // cols {-2,-1,0,1,2,3,167,...,172} x 171 (negative cols hit zeroed pads/guard)
  for (int i = tid; i < 12 * 171; i += 512) {
    int j = i / 171, u = i - j * 171;
    int c = (j < 6) ? (j - 2) : (j + 161);
    cX[i] = Xp[(ptrdiff_t)u * PHP + c];
    cY[i] = Yp[(ptrdiff_t)u * PHP + c];
  }
  __syncthreads();

  auto xri  = [](int r) { return (r < 4) ? r : r - 163; };
  auto cidx = [](int c) { return (c <= 3) ? c + 2 : c - 161; };
  auto Xv = [&](int r, int c) -> float {
    if (r < 0 || r > 170 || c < 0) return 0.f;
    return rX[xri(r) * 176 + c];
  };
  auto Yv = [&](int r, int c) -> float {
    if (r < 0 || r > 170 || c < 0) return 0.f;
    return rY[xri(r) * 176 + c];
  };

  // ---- strips: one per thread (424 total) ----
  if (tid < 424) {
    float sum = 0.f;
    if (tid < 200) {  // YX: first=Y(pr), second=X(la)
      int line = tid / 25, j = tid - line * 25;
      int ay = j / 5 - 2, ax = (j % 5) - 2;
      if (line < 4) {
        int u = (line < 2) ? line : line + 167;
        int ri = xri(u), r2 = u + ay;
        if (r2 >= 0 && r2 <= 170) {
          int ri2 = xri(r2);
          for (int v = 0; v < 171; ++v) {
            int c2 = v + ax;
            float x = (c2 >= 0) ? rX[ri2 * 176 + c2] : 0.f;
            sum += rY[ri * 176 + v] * x;
          }
        }
      } else {
        int v = ((line - 4) < 2) ? (line - 4) : (line - 4) + 167;
        int yc = cidx(v), xc = cidx(v + ax);
        for (int u = 0; u < 171; ++u) {
          int r2 = u + ay;
          float x = (r2 >= 0 && r2 <= 170) ? cX[xc * 171 + r2] : 0.f;
          sum += cY[yc * 171 + u] * x;
        }
      }
    } else if (tid < 304) {  // XX (la)
      int t2 = tid - 200;
      int line = t2 / 13, j13 = t2 - line * 13;
      int ay = (j13 < 3) ? 0 : ((j13 < 8) ? 1 : 2);
      int ax = (j13 < 3) ? j13 : ((j13 < 8) ? j13 - 5 : j13 - 10);
      if (line < 4) {
        int u = (line < 2) ? line : line + 167;
        int ri = xri(u), r2 = u + ay;
        if (r2 <= 170) {
          int ri2 = xri(r2);
          for (int v = 0; v < 171; ++v) {
            int c2 = v + ax;
            float x = (c2 >= 0) ? rX[ri2 * 176 + c2] : 0.f;
            sum += rX[ri * 176 + v] * x;
          }
        }
      } else {
        int v = ((line - 4) < 2) ? (line - 4) : (line - 4) + 167;
        int c1 = cidx(v), c2i = cidx(v + ax);
        for (int u = 0; u < 171; ++u) {
          int r2 = u + ay;
          float x = (r2 <= 170) ? cX[c2i * 171 + r2] : 0.f;
          sum += cX[c1 * 171 + u] * x;
        }
      }
    } else if (tid < 408) {  // YY (pr)
      int t2 = tid - 304;
      int line = t2 / 13, j13 = t2 - line * 13;
      int ay = (j13 < 3) ? 0 : ((j13 < 8) ? 1 : 2);
      int ax = (j13 < 3) ? j13 : ((j13 < 8) ? j13 - 5 : j13 - 10);
      if (line < 4) {
        int u = (line < 2) ? line : line + 167;
        int ri = xri(u), r2 = u + ay;
        if (r2 <= 170) {
          int ri2 = xri(r2);
          for (int v = 0; v < 171; ++v) {
            int c2 = v + ax;
            float y = (c2 >= 0) ? rY[ri2 * 176 + c2] : 0.f;
            sum += rY[ri * 176 + v] * y;
          }
        }
      } else {
        int v = ((line - 4) < 2) ? (line - 4) : (line - 4) + 167;
        int c1 = cidx(v), c2i = cidx(v + ax);
        for (int u = 0; u < 171; ++u) {
          int r2 = u + ay;
          float y = (r2 <= 170) ? cY[c2i * 171 + r2] : 0.f;
          sum += cY[c1 * 171 + u] * y;
        }
      }
    } else if (tid < 416) {  // X plane line sums
      int line = tid - 408;
      if (line < 4) {
        int u = (line < 2) ? line : line + 167;
        int ri = xri(u);
        for (int v = 0; v < 171; ++v) sum += rX[ri * 176 + v];
      } else {
        int v = ((line - 4) < 2) ? (line - 4) : (line - 4) + 167;
        int xc = cidx(v);
        for (int u = 0; u < 171; ++u) sum += cX[xc * 171 + u];
      }
    } else {  // Y plane line sums
      int line = tid - 416;
      if (line < 4) {
        int u = (line < 2) ? line : line + 167;
        int ri = xri(u);
        for (int v = 0; v < 171; ++v) sum += rY[ri * 176 + v];
      } else {
        int v = ((line - 4) < 2) ? (line - 4) : (line - 4) + 167;
        int yc = cidx(v);
        for (int u = 0; u < 171; ++u) sum += cY[yc * 171 + u];
      }
    }
    sres[tid] = sum;
  }
  __syncthreads();

  // ---- assembly ----
  float* s = cov + (size_t)nc * 192;
  const float* tt = tot + (size_t)nc * 64;
  auto uline = [](int u) { return (u < 2) ? u : u - 167; };
  const int ex0[3] = {169, 0, 0};
  const int ex1[3] = {170, 170, 1};

  if (tid < 81) {  // pr[d] * la[e]
    int d = tid / 9, e = tid - 9 * d;
    int dy = d / 3, dx = d - 3 * dy, ey = e / 3, ex = e - 3 * ey;
    int ay = ey - dy, ax = ex - dx;
    int j = (ay + 2) * 5 + (ax + 2);
    int ra = ex0[dy], rb = ex1[dy], ca = ex0[dx], cb = ex1[dx];
    float S = tt[28 + j];
    S -= sres[uline(ra) * 25 + j] + sres[uline(rb) * 25 + j];
    S -= sres[(4 + uline(ca)) * 25 + j] + sres[(4 + uline(cb)) * 25 + j];
    S += Yv(ra, ca) * Xv(ra + ay, ca + ax) + Yv(ra, cb) * Xv(ra + ay, cb + ax);
    S += Yv(rb, ca) * Xv(rb + ay, ca + ax) + Yv(rb, cb) * Xv(rb + ay, cb + ax);
    s[108 + tid] = S;
  } else if (tid < 126) {  // la*la UT45
    int k = tid - 81, kk = k, d = 0;
    while (kk >= 9 - d) { kk -= 9 - d; ++d; }
    int e = d + kk;
    int dy = d / 3, dx = d - 3 * dy, ey = e / 3, ex = e - 3 * ey;
    int ay = ey - dy, ax = ex - dx;
    int j13 = (ay == 0) ? ax : ((ay == 1) ? 5 + ax : 10 + ax);
    int ra = ex0[dy], rb = ex1[dy], ca = ex0[dx], cb = ex1[dx];
    float S = tt[2 + j13];
    S -= sres[200 + uline(ra) * 13 + j13] + sres[200 + uline(rb) * 13 + j13];
    S -= sres[200 + (4 + uline(ca)) * 13 + j13] +
         sres[200 + (4 + uline(cb)) * 13 + j13];
    S += Xv(ra, ca) * Xv(ra + ay, ca + ax) + Xv(ra, cb) * Xv(ra + ay, cb + ax);
    S += Xv(rb, ca) * Xv(rb + ay, ca + ax) + Xv(rb, cb) * Xv(rb + ay, cb + ax);
    s[18 + k] = S;
  } else if (tid < 171) {  // pr*pr UT45
    int k = tid - 126, kk = k, d = 0;
    while (kk >= 9 - d) { kk -= 9 - d; ++d; }
    int e = d + kk;
    int dy = d / 3, dx = d - 3 * dy, ey = e / 3, ex = e - 3 * ey;
    int ay = ey - dy, ax = ex - dx;
    int j13 = (ay == 0) ? ax : ((ay == 1) ? 5 + ax : 10 + ax);
    int ra = ex0[dy], rb = ex1[dy], ca = ex0[dx], cb = ex1[dx];
    float S = tt[15 + j13];
    S -= sres[304 + uline(ra) * 13 + j13] + sres[304 + uline(rb) * 13 + j13];
    S -= sres[304 + (4 + uline(ca)) * 13 + j13] +
         sres[304 + (4 + uline(cb)) * 13 + j13];
    S += Yv(ra, ca) * Yv(ra + ay, ca + ax) + Yv(ra, cb) * Yv(ra + ay, cb + ax);
    S += Yv(rb, ca) * Yv(rb + ay, ca + ax) + Yv(rb, cb) * Yv(rb + ay, cb + ax);
    s[63 + k] = S;
  } else if (tid < 180) {  // sum la
    int d = tid - 171;
    int dy = d / 3, dx = d - 3 * dy;
    int ra = ex0[dy], rb = ex1[dy], ca = ex0[dx], cb = ex1[dx];
    float S = tt[0];
    S -= sres[408 + uline(ra)] + sres[408 + uline(rb)];
    S -= sres[408 + 4 + uline(ca)] + sres[408 + 4 + uline(cb)];
    S += Xv(ra, ca) + Xv(ra, cb) + Xv(rb, ca) + Xv(rb, cb);
    s[d] = S;
  } else if (tid < 189) {  // sum pr
    int d = tid - 180;
    int dy = d / 3, dx = d - 3 * dy;
    int ra = ex0[dy], rb = ex1[dy], ca = ex0[dx], cb = ex1[dx];
    float S = tt[1];
    S -= sres[416 + uline(ra)] + sres[416 + uline(rb)];
    S -= sres[416 + 4 + uline(ca)] + sres[416 + 4 + uline(cb)];
    S += Yv(ra, ca) + Yv(ra, cb) + Yv(rb, ca) + Yv(rb, cb);
    s[9 + d] = S;
  }
}

// ---------------------------------------------------------------------------
// Stage 3 (round-9 proven, unchanged): fp64 in LDS, Cholesky(la_cov+1e-5),
// triangular solve, Schur + 1e-6 I, Cholesky logdet -> cov[nc*192+190..191].
// ---------------------------------------------------------------------------
__global__ __launch_bounds__(64) void stage3_rmi(float* __restrict__ covp) {
  int nc  = blockIdx.x;
  int tid = threadIdx.x;
  const float* s = covp + (size_t)nc * 192;
  __shared__ double lc[81], pc[81], plc[81], mla[9], mpr[9];
  const double Minv = 1.0 / (double)MM;

  if (tid < 9)       mla[tid]     = (double)s[tid] * Minv;
  else if (tid < 18) mpr[tid - 9] = (double)s[tid] * Minv;
  __syncthreads();

  for (int e = tid; e < 81; e += 64) {
    int r = e / 9, c = e - 9 * (e / 9);
    int lo = r < c ? r : c, hi = r < c ? c : r;
    int k = lo * 9 - lo * (lo - 1) / 2 + (hi - lo);
    double a = (double)s[18 + k] * Minv - mla[r] * mla[c];
    if (r == c) a += 1e-5;
    lc[e] = a;
    pc[e] = (double)s[63 + k] * Minv - mpr[r] * mpr[c];
    plc[e] = (double)s[108 + e] * Minv - mpr[r] * mla[c];
  }
  __syncthreads();

  for (int j = 0; j < 9; ++j) {
    if (tid == 0) lc[j * 9 + j] = sqrt(lc[j * 9 + j]);
    __syncthreads();
    if (tid > j && tid < 9) lc[tid * 9 + j] /= lc[j * 9 + j];
    __syncthreads();
    if (tid > j && tid < 9) {
      double lij = lc[tid * 9 + j];
      for (int k = j + 1; k <= tid; ++k) lc[tid * 9 + k] -= lij * lc[k * 9 + j];
    }
    __syncthreads();
  }

  if (tid < 9) {
    int d = tid;
    for (int j = 0; j < 9; ++j) {
      double t = plc[d * 9 + j];
      for (int k = 0; k < j; ++k) t -= plc[d * 9 + k] * lc[j * 9 + k];
      plc[d * 9 + j] = t / lc[j * 9 + j];
    }
  }
  __syncthreads();

  for (int e = tid; e < 81; e += 64) {
    int r = e / 9, c = e - 9 * (e / 9);
    double a = pc[e];
    for (int f = 0; f < 9; ++f) a -= plc[r * 9 + f] * plc[c * 9 + f];
    if (r == c) a += 1e-6;
    pc[e] = a;
  }
  __syncthreads();

  for (int j = 0; j < 9; ++j) {
    if (tid == 0) pc[j * 9 + j] = sqrt(pc[j * 9 + j]);
    __syncthreads();
    if (tid > j && tid < 9) pc[tid * 9 + j] /= pc[j * 9 + j];
    __syncthreads();
    if (tid > j && tid < 9) {
      double lij = pc[tid * 9 + j];
      for (int k = j + 1; k <= tid; ++k) pc[tid * 9 + k] -= lij * pc[k * 9 + j];
    }
    __syncthreads();
  }

  if (tid == 0) {
    double sl = 0.0;
    for (int j = 0; j < 9; ++j) sl += log(pc[j * 9 + j] + 1e-8);
    *(double*)(covp + (size_t)nc * 192 + 190) = sl;
  }
}

// ---------------------------------------------------------------------------
// Stage 4: reduce 76 fp64 partials -> out[0] = sum / (N * NUM_CLASSES)
// ---------------------------------------------------------------------------
__global__ __launch_bounds__(64) void stage4_reduce(
    const float* __restrict__ covp, float* __restrict__ out) {
  int tid = threadIdx.x;
  double v = 0.0;
  if (tid < NNC)
    v = *(const double*)(covp + (size_t)tid * 192 + 190);
  if (tid + 64 < NNC)
    v += *(const double*)(covp + (size_t)(tid + 64) * 192 + 190);
#pragma unroll
  for (int o = 32; o > 0; o >>= 1) v += __shfl_down(v, o, 64);
  if (tid == 0) out[0] = (float)(v / (double)NNC);
}

// ---------------------------------------------------------------------------
extern "C" void kernel_launch(void* const* d_in, const int* in_sizes, int n_in,
                              void* d_out, int out_size, void* d_ws, size_t ws_size,
                              hipStream_t stream) {
  const float* cls  = (const float*)d_in[0];
  const int* label  = (const int*)d_in[1];
  float* out = (float*)d_out;

  float* base = (float*)d_ws;
  float* P    = base + 16;                           // guard: base[0..15]=0
  float* L    = P + (size_t)NNC * PP2A;
  float* tot  = L + (size_t)NNC * PP2A;              // 76*64 f32
  float* cov  = tot + (size_t)NNC * 64;              // 76*192 f32

  stage1_pool<<<NBATCH * PH, 512, 0, stream>>>(cls, label, base, P, L);
  dim3 g2(NNC, 3, 1);
  stage2_tot<<<g2, 512, 0, stream>>>(P, L, tot);
  stage2b_asm<<<NNC, 512, 0, stream>>>(P, L, tot, cov);
  stage3_rmi<<<NNC, 64, 0, stream>>>(cov);
  stage4_reduce<<<1, 64, 0, stream>>>(cov, out);
}